// Round 9
// baseline (1942.612 us; speedup 1.0000x reference)
//
#include <hip/hip_runtime.h>
#include <hip/hip_bf16.h>
#include <cmath>
#include <cstdint>

#define B_  2
#define T_  1024
#define V_  32000
#define D_  1024
#define H_  16
#define L_  8
#define DH_ 64

typedef __attribute__((ext_vector_type(8))) short bf16x8;
typedef __attribute__((ext_vector_type(4))) float f32x4;

__device__ __forceinline__ ushort f2bf(float f) {
    union { float f; uint32_t u; } v; v.f = f;
    uint32_t r = v.u + 0x7FFFu + ((v.u >> 16) & 1u);
    return (ushort)(r >> 16);
}
__device__ __forceinline__ float bf2f(ushort u) {
    union { uint32_t u; float f; } v; v.u = ((uint32_t)u) << 16;
    return v.f;
}

__device__ __forceinline__ void async_copy16(const void* g, void* l) {
    __builtin_amdgcn_global_load_lds(
        (const __attribute__((address_space(1))) void*)g,
        (__attribute__((address_space(3))) void*)l, 16, 0, 0);
}

// ---------------- fp32 -> bf16 cast (weights) ----------------
__global__ __launch_bounds__(256) void k_cast(const float4* __restrict__ in,
                                              ushort4* __restrict__ out, int n4) {
    for (int i = blockIdx.x * 256 + threadIdx.x; i < n4; i += gridDim.x * 256) {
        float4 v = in[i];
        out[i] = make_ushort4(f2bf(v.x), f2bf(v.y), f2bf(v.z), f2bf(v.w));
    }
}

// ---------------- RoPE tables: cos/sin (T, 32) ----------------
__global__ void k_rope_tables(float* __restrict__ cosT, float* __restrict__ sinT) {
    int t = blockIdx.x;
    int i = threadIdx.x;           // 0..31
    float invf = (i < 16) ? powf(1000.0f, -(float)i / 16.0f) : 0.0f;
    float th = (float)t * invf;
    cosT[t * 32 + i] = cosf(th);
    sinT[t * 32 + i] = sinf(th);
}

// ---------------- Embedding gather: fp32 x, bf16 mirror, row sum-of-squares ----------------
__global__ __launch_bounds__(256) void k_gather(const int* __restrict__ idx,
                                                const float* __restrict__ emb,
                                                float* __restrict__ x,
                                                ushort* __restrict__ xb,
                                                float* __restrict__ ss) {
    int row = blockIdx.x;
    int id = idx[row];
    float4 v = ((const float4*)(emb + (size_t)id * D_))[threadIdx.x];
    ((float4*)(x + (size_t)row * D_))[threadIdx.x] = v;
    *(ushort4*)(xb + (size_t)row * D_ + threadIdx.x * 4) =
        make_ushort4(f2bf(v.x), f2bf(v.y), f2bf(v.z), f2bf(v.w));
    float s = v.x * v.x + v.y * v.y + v.z * v.z + v.w * v.w;
    #pragma unroll
    for (int off = 1; off < 64; off <<= 1) s += __shfl_xor(s, off);
    __shared__ float wsum[4];
    int lane = threadIdx.x & 63, wv = threadIdx.x >> 6;
    if (lane == 0) wsum[wv] = s;
    __syncthreads();
    if (threadIdx.x == 0) ss[row] = wsum[0] + wsum[1] + wsum[2] + wsum[3];
}

// ---------------- MFMA GEMM: C[m,n] = epi( sc[m] * sum_k A[m,k]*W[n,k] ) ----------------
// BM=128, BK=64, XOR-swizzled LDS (T2), XCD swizzle (T1).
// BN<=128: prefetch double-buffer. BN=256: single buffer, high-intensity tile.
// EPI: 0 none(+nontemporal), 1 +Res(fp32), 2 relu^2, 3 RoPE(qkv).
// RSCALE: scale rows by rsqrt(ssIn[row]/D+eps) (fused RMSNorm).
// SSOUT (EPI==1 only): write bf16 mirror xbOut and atomicAdd row sum-of-squares to ssOut.
template<int BN, int EPI, bool OUTBF, bool CONVB, bool RSCALE, bool SSOUT>
__global__ __launch_bounds__(256, 2) void k_mfma_gemm(const ushort* __restrict__ A,
                                                      const void* __restrict__ Wp,
                                                      void* __restrict__ Cp,
                                                      const float* __restrict__ Res,
                                                      const float* __restrict__ cosT,
                                                      const float* __restrict__ sinT,
                                                      const float* __restrict__ ssIn,
                                                      float* __restrict__ ssOut,
                                                      ushort* __restrict__ xbOut,
                                                      int M, int N, int K) {
    constexpr int BM = 128;
    constexpr int MI = 4;
    constexpr int NI = BN / 32;
    constexpr bool DBUF = (BN <= 128);
    constexpr int NB = DBUF ? 2 : 1;
    __shared__ ushort As[NB][BM][64];   // swizzled: chunk c of row r at byte ((c^(r&7))<<4)
    __shared__ ushort Bs[NB][BN][64];
    const int tid = threadIdx.x;
    const int wid = tid >> 6, lane = tid & 63;
    const int wr = wid >> 1, wc = wid & 1;
    const int r16 = lane & 15, kc = lane >> 4;
    const int rx = (r16 & 7) << 4;
    const int srow8 = tid >> 3;
    const int sdcp = tid & 7;

    // T1: XCD-aware block swizzle (valid when nwg % 8 == 0)
    const int nwg = gridDim.x * gridDim.y;
    int orig = blockIdx.y * gridDim.x + blockIdx.x;
    int swz = (nwg & 7) ? orig : ((orig & 7) * (nwg >> 3) + (orig >> 3));
    const size_t bm = (size_t)(swz % gridDim.x) * BM;
    const size_t bn = (size_t)(swz / gridDim.x) * BN;

    auto stage = [&](int buf, int k0) {
        #pragma unroll
        for (int i = 0; i < 4; i++) {
            const int row = i * 32 + srow8;
            const ushort* g = A + (bm + row) * (size_t)K + k0 + ((sdcp ^ (row & 7)) * 8);
            async_copy16(g, (char*)As + buf * (BM * 128) + (i * 256 + tid) * 16);
        }
        if constexpr (!CONVB) {
            const ushort* Wb = (const ushort*)Wp;
            #pragma unroll
            for (int i = 0; i < BN / 32; i++) {
                const int row = i * 32 + srow8;
                const ushort* g = Wb + (bn + row) * (size_t)K + k0 + ((sdcp ^ (row & 7)) * 8);
                async_copy16(g, (char*)Bs + buf * (BN * 128) + (i * 256 + tid) * 16);
            }
        } else {
            const float* Wf = (const float*)Wp;
            #pragma unroll
            for (int i = 0; i < BN / 32; i++) {
                const int row = i * 32 + srow8;
                const float* src = Wf + (bn + row) * (size_t)K + k0 + sdcp * 8;
                float4 v0 = *(const float4*)(src);
                float4 v1 = *(const float4*)(src + 4);
                union { ushort u[8]; bf16x8 v; } tmp;
                tmp.u[0] = f2bf(v0.x); tmp.u[1] = f2bf(v0.y);
                tmp.u[2] = f2bf(v0.z); tmp.u[3] = f2bf(v0.w);
                tmp.u[4] = f2bf(v1.x); tmp.u[5] = f2bf(v1.y);
                tmp.u[6] = f2bf(v1.z); tmp.u[7] = f2bf(v1.w);
                *(bf16x8*)((char*)Bs + buf * (BN * 128) + row * 128 + ((sdcp ^ (row & 7)) << 4)) = tmp.v;
            }
        }
    };

    f32x4 acc[MI][NI];
    #pragma unroll
    for (int mi = 0; mi < MI; mi++)
        #pragma unroll
        for (int ni = 0; ni < NI; ni++) {
            f32x4 z = {0.f, 0.f, 0.f, 0.f};
            acc[mi][ni] = z;
        }

    auto compute = [&](int buf) {
        #pragma unroll
        for (int kk = 0; kk < 2; kk++) {
            bf16x8 af[MI], bfr[NI];
            #pragma unroll
            for (int mi = 0; mi < MI; mi++)
                af[mi] = *(const bf16x8*)((const char*)As + buf * (BM * 128) +
                                          (wr * 64 + mi * 16 + r16) * 128 +
                                          ((kk * 64 + kc * 16) ^ rx));
            #pragma unroll
            for (int ni = 0; ni < NI; ni++)
                bfr[ni] = *(const bf16x8*)((const char*)Bs + buf * (BN * 128) +
                                           (wc * (BN / 2) + ni * 16 + r16) * 128 +
                                           ((kk * 64 + kc * 16) ^ rx));
            #pragma unroll
            for (int mi = 0; mi < MI; mi++)
                #pragma unroll
                for (int ni = 0; ni < NI; ni++)
                    acc[mi][ni] = __builtin_amdgcn_mfma_f32_16x16x32_bf16(af[mi], bfr[ni],
                                                                          acc[mi][ni], 0, 0, 0);
        }
    };

    const int KSTEPS = K >> 6;
    if constexpr (DBUF) {
        stage(0, 0);
        __syncthreads();
        for (int step = 0; step < KSTEPS; ++step) {
            const int cur = step & 1;
            if (step + 1 < KSTEPS) stage(cur ^ 1, (step + 1) << 6);
            compute(cur);
            __syncthreads();
        }
    } else {
        for (int step = 0; step < KSTEPS; ++step) {
            stage(0, step << 6);
            __syncthreads();
            compute(0);
            __syncthreads();
        }
    }

    // epilogue: D frag row=(lane>>4)*4+j, col=lane&15
    #pragma unroll
    for (int mi = 0; mi < MI; mi++) {
        #pragma unroll
        for (int j = 0; j < 4; j++) {
            const size_t row = bm + wr * 64 + mi * 16 + (lane >> 4) * 4 + j;
            if constexpr (RSCALE) {
                const float sc = rsqrtf(ssIn[row] * (1.0f / 1024.0f) + 1e-6f);
                #pragma unroll
                for (int ni = 0; ni < NI; ni++) acc[mi][ni][j] *= sc;
            }
            if constexpr (EPI == 3) {
                // RoPE on q,k sections. Wave col-span = 64 = one head; pairs (i,i+32) in (np,np+2).
                static_assert(BN == 128, "rope epilogue assumes BN=128");
                const int sec = (int)((bn + wc * 64) >> 10);   // 0=q,1=k,2=v
                if (sec < 2) {
                    const int t = (int)(row & (T_ - 1));
                    #pragma unroll
                    for (int np = 0; np < 2; np++) {
                        const int i1 = np * 16 + r16;          // 0..31
                        float c = cosT[t * 32 + i1], s = sinT[t * 32 + i1];
                        float x1 = acc[mi][np][j], x2 = acc[mi][np + 2][j];
                        acc[mi][np][j]     = c * x1 - s * x2;
                        acc[mi][np + 2][j] = s * x1 + c * x2;
                    }
                }
            }
            float ssq = 0.f;
            #pragma unroll
            for (int ni = 0; ni < NI; ni++) {
                const size_t col = bn + wc * (BN / 2) + ni * 16 + r16;
                float v = acc[mi][ni][j];
                if constexpr (EPI == 1) v += Res[row * N + col];
                if constexpr (EPI == 2) { v = fmaxf(v, 0.f); v *= v; }
                if constexpr (SSOUT) {
                    ssq += v * v;
                    xbOut[row * N + col] = f2bf(v);
                }
                if constexpr (OUTBF) {
                    ((ushort*)Cp)[row * N + col] = f2bf(v);
                } else if constexpr (EPI == 0) {
                    __builtin_nontemporal_store(v, (float*)Cp + row * N + col);
                } else {
                    ((float*)Cp)[row * N + col] = v;
                }
            }
            if constexpr (SSOUT) {
                #pragma unroll
                for (int off = 1; off < 16; off <<= 1) ssq += __shfl_xor(ssq, off);
                if (r16 == 0) atomicAdd(&ssOut[row], ssq);
            }
        }
    }
}

// ---------------- MFMA flash attention: paired causal tiles ----------------
__global__ __launch_bounds__(256) void k_attn_pair(const ushort* __restrict__ qkv,
                                                   ushort* __restrict__ ctx) {
    __shared__ __align__(16) char lds[32768];
    // [0,8K): K[64key][64d] swz | [8K,16K): Vt[64d][64key] swz
    // [16K,24K): Qlo then Plo | [24K,32K): Qhi then Phi   (all 128B rows)
    const int tid = threadIdx.x;
    const int w = tid >> 6, lane = tid & 63;
    const int r16 = lane & 15, kc = lane >> 4;
    const int rx = (r16 & 7) << 4;
    const int ip = blockIdx.x;                 // pair index 0..7
    const int qb[2] = { ip * 64, (15 - ip) * 64 };   // 0=lo, 1=hi
    const int bh = blockIdx.y, b = bh >> 4, h = bh & 15;
    const size_t tok0 = (size_t)b * T_;
    const ushort* kg = qkv + tok0 * (3 * D_) + D_ + h * DH_;
    const ushort* vg = qkv + tok0 * (3 * D_) + 2 * D_ + h * DH_;
    const float SCALE_LOG2E = 0.125f * 1.44269504089f;

    #pragma unroll
    for (int t = 0; t < 2; t++) {
        const ushort* qg = qkv + (tok0 + qb[t]) * (3 * D_) + h * DH_;
        #pragma unroll
        for (int i = 0; i < 2; i++) {
            int slot = i * 256 + tid;
            int row = slot >> 3, dcp = slot & 7;
            int d0 = (dcp ^ (row & 7)) * 8;
            async_copy16(qg + (size_t)row * (3 * D_) + d0, lds + 16384 + t * 8192 + slot * 16);
        }
    }
    __syncthreads();
    bf16x8 aq[2][2];
    #pragma unroll
    for (int t = 0; t < 2; t++)
        #pragma unroll
        for (int ks = 0; ks < 2; ks++) {
            int row = w * 16 + r16;
            aq[t][ks] = *(const bf16x8*)(lds + 16384 + t * 8192 + row * 128 +
                                         ((ks * 64 + kc * 16) ^ rx));
        }

    f32x4 o[2][4];
    float m[2][4], l[2][4];
    #pragma unroll
    for (int t = 0; t < 2; t++)
        #pragma unroll
        for (int nd = 0; nd < 4; nd++) {
            f32x4 z = {0.f, 0.f, 0.f, 0.f};
            o[t][nd] = z;
            m[t][nd] = -1e30f; l[t][nd] = 0.f;
        }

    const int nch = 16 - ip;                   // chunks for hi tile
    for (int ch = 0; ch < nch; ch++) {
        const int kb = ch << 6;
        __syncthreads();
        #pragma unroll
        for (int i = 0; i < 2; i++) {
            int slot = i * 256 + tid;
            int row = slot >> 3, dcp = slot & 7;
            int d0 = (dcp ^ (row & 7)) * 8;
            async_copy16(kg + (size_t)(kb + row) * (3 * D_) + d0, lds + slot * 16);
        }
        {
            int key = tid >> 2, dbase = (tid & 3) * 16;
            const ushort* src = vg + (size_t)(kb + key) * (3 * D_) + dbase;
            bf16x8 v0 = *(const bf16x8*)(src);
            bf16x8 v1 = *(const bf16x8*)(src + 8);
            #pragma unroll
            for (int e = 0; e < 8; e++) {
                int d = dbase + e;
                *(ushort*)(lds + 8192 + d * 128 + ((key * 2) ^ ((d & 7) << 4))) = (ushort)v0[e];
                d = dbase + 8 + e;
                *(ushort*)(lds + 8192 + d * 128 + ((key * 2) ^ ((d & 7) << 4))) = (ushort)v1[e];
            }
        }
        __syncthreads();

        const int nact = (ch <= ip) ? 2 : 1;
        for (int tt = 0; tt < nact; tt++) {
            const int t = (tt == 0) ? 1 : 0;   // hi first, then lo
            const int pq = 16384 + t * 8192;
            f32x4 s[4];
            #pragma unroll
            for (int ni = 0; ni < 4; ni++) { f32x4 z = {0.f, 0.f, 0.f, 0.f}; s[ni] = z; }
            __builtin_amdgcn_s_setprio(1);
            #pragma unroll
            for (int ks = 0; ks < 2; ks++)
                #pragma unroll
                for (int ni = 0; ni < 4; ni++) {
                    int row = ni * 16 + r16;
                    bf16x8 kf = *(const bf16x8*)(lds + row * 128 + ((ks * 64 + kc * 16) ^ rx));
                    s[ni] = __builtin_amdgcn_mfma_f32_16x16x32_bf16(aq[t][ks], kf, s[ni], 0, 0, 0);
                }
            __builtin_amdgcn_s_setprio(0);

            const bool diag = (kb == qb[t]);
            float corr[4];
            #pragma unroll
            for (int j = 0; j < 4; j++) {
                const int qrow = qb[t] + w * 16 + kc * 4 + j;
                #pragma unroll
                for (int ni = 0; ni < 4; ni++) {
                    float v = s[ni][j] * SCALE_LOG2E;
                    if (diag) { int key = kb + ni * 16 + r16; if (key > qrow) v = -1e30f; }
                    s[ni][j] = v;
                }
                float tmax = fmaxf(fmaxf(s[0][j], s[1][j]), fmaxf(s[2][j], s[3][j]));
                #pragma unroll
                for (int off = 1; off < 16; off <<= 1) tmax = fmaxf(tmax, __shfl_xor(tmax, off));
                float mn = fmaxf(m[t][j], tmax);
                corr[j] = exp2f(m[t][j] - mn);
                m[t][j] = mn;
                float ps = 0.f;
                #pragma unroll
                for (int ni = 0; ni < 4; ni++) {
                    float p = exp2f(s[ni][j] - mn);
                    s[ni][j] = p;
                    ps += p;
                }
                #pragma unroll
                for (int off = 1; off < 16; off <<= 1) ps += __shfl_xor(ps, off);
                l[t][j] = l[t][j] * corr[j] + ps;
            }
            #pragma unroll
            for (int ni = 0; ni < 4; ni++)
                #pragma unroll
                for (int j = 0; j < 4; j++) {
                    int row = w * 16 + kc * 4 + j;
                    *(ushort*)(lds + pq + row * 128 + ((ni * 32 + r16 * 2) ^ ((row & 7) << 4))) = f2bf(s[ni][j]);
                }
            #pragma unroll
            for (int nd = 0; nd < 4; nd++)
                #pragma unroll
                for (int j = 0; j < 4; j++) o[t][nd][j] *= corr[j];
            __builtin_amdgcn_s_setprio(1);
            #pragma unroll
            for (int ks = 0; ks < 2; ks++) {
                int prow = w * 16 + r16;
                bf16x8 pf = *(const bf16x8*)(lds + pq + prow * 128 + ((ks * 64 + kc * 16) ^ rx));
                #pragma unroll
                for (int nd = 0; nd < 4; nd++) {
                    int drow = nd * 16 + r16;
                    bf16x8 vf = *(const bf16x8*)(lds + 8192 + drow * 128 + ((ks * 64 + kc * 16) ^ rx));
                    o[t][nd] = __builtin_amdgcn_mfma_f32_16x16x32_bf16(pf, vf, o[t][nd], 0, 0, 0);
                }
            }
            __builtin_amdgcn_s_setprio(0);
        }
    }

    #pragma unroll
    for (int t = 0; t < 2; t++)
        #pragma unroll
        for (int j = 0; j < 4; j++) {
            float inv = 1.0f / l[t][j];
            int row = qb[t] + w * 16 + kc * 4 + j;
            ushort* dst = ctx + (tok0 + row) * D_ + h * DH_;
            #pragma unroll
            for (int nd = 0; nd < 4; nd++)
                dst[nd * 16 + r16] = f2bf(o[t][nd][j] * inv);
        }
}

extern "C" void kernel_launch(void* const* d_in, const int* in_sizes, int n_in,
                              void* d_out, int out_size, void* d_ws, size_t ws_size,
                              hipStream_t stream) {
    const int*   xi   = (const int*)d_in[0];
    const float* emb  = (const float*)d_in[1];
    const float* Wqkv = (const float*)d_in[2];
    const float* Wout = (const float*)d_in[3];
    const float* W1   = (const float*)d_in[4];
    const float* W2   = (const float*)d_in[5];
    const float* lmh  = (const float*)d_in[6];
    float* out = (float*)d_out;

    const size_t NT = (size_t)B_ * T_;
    size_t off = 0;
    auto carve = [&](size_t bytes) -> char* {
        char* r = (char*)d_ws + off;
        off += (bytes + 255) & ~(size_t)255;
        return r;
    };
    float*  xbuf = (float*)carve(NT * D_ * 4);
    ushort* xb   = (ushort*)carve(NT * D_ * 2);     // bf16 mirror of residual stream
    ushort* qkv  = (ushort*)carve(NT * 3 * D_ * 2);
    ushort* ctxb = (ushort*)carve(NT * D_ * 2);
    ushort* hb   = (ushort*)carve(NT * 4 * D_ * 2);
    float*  cosT = (float*)carve(T_ * 32 * 4);
    float*  sinT = (float*)carve(T_ * 32 * 4);
    float*  ssA  = (float*)carve(17 * NT * 4);      // ss_q[0..8] then ss_f[0..7]
    float*  ss_q = ssA;                             // slot l: input to qkv layer l; slot 8: lm_head
    float*  ss_f = ssA + 9 * NT;                    // slot l: input to FFN layer l

    const size_t nWqkv = (size_t)L_ * 3 * D_ * D_;
    const size_t nWout = (size_t)L_ * D_ * D_;
    const size_t nW1   = (size_t)L_ * 4 * D_ * D_;
    const size_t nW2   = (size_t)L_ * 4 * D_ * D_;
    const size_t nLmh  = (size_t)V_ * D_;
    ushort* WqkvB = (ushort*)carve(nWqkv * 2);
    ushort* WoutB = (ushort*)carve(nWout * 2);
    ushort* W1B   = (ushort*)carve(nW1 * 2);
    ushort* W2B   = (ushort*)carve(nW2 * 2);
    ushort* lmhB  = (ushort*)carve(nLmh * 2);
    const bool preconv = (off <= ws_size);

    hipMemsetAsync(ssA, 0, 17 * NT * 4, stream);

    if (preconv) {
        k_cast<<<dim3(2048), dim3(256), 0, stream>>>((const float4*)Wqkv, (ushort4*)WqkvB, (int)(nWqkv / 4));
        k_cast<<<dim3(2048), dim3(256), 0, stream>>>((const float4*)Wout, (ushort4*)WoutB, (int)(nWout / 4));
        k_cast<<<dim3(2048), dim3(256), 0, stream>>>((const float4*)W1,   (ushort4*)W1B,   (int)(nW1 / 4));
        k_cast<<<dim3(2048), dim3(256), 0, stream>>>((const float4*)W2,   (ushort4*)W2B,   (int)(nW2 / 4));
        k_cast<<<dim3(2048), dim3(256), 0, stream>>>((const float4*)lmh,  (ushort4*)lmhB,  (int)(nLmh / 4));
    }

#define LAUNCH_GEMM(BN, EPI, OUTBF, RSC, SSO, GX, GY, Aq, Wb16, Wf32, Cq, Rq, ssin, ssout, xbo, Mv, Nv, Kv) \
    do {                                                                                     \
        if (preconv)                                                                         \
            k_mfma_gemm<BN, EPI, OUTBF, false, RSC, SSO><<<dim3(GX, GY), dim3(256), 0, stream>>>( \
                (const ushort*)(Aq), (const void*)(Wb16), (void*)(Cq), (Rq), cosT, sinT,     \
                (ssin), (ssout), (xbo), Mv, Nv, Kv);                                         \
        else                                                                                 \
            k_mfma_gemm<BN, EPI, OUTBF, true, RSC, SSO><<<dim3(GX, GY), dim3(256), 0, stream>>>( \
                (const ushort*)(Aq), (const void*)(Wf32), (void*)(Cq), (Rq), cosT, sinT,     \
                (ssin), (ssout), (xbo), Mv, Nv, Kv);                                         \
    } while (0)

    k_rope_tables<<<dim3(T_), dim3(32), 0, stream>>>(cosT, sinT);
    k_gather<<<dim3(NT), dim3(256), 0, stream>>>(xi, emb, xbuf, xb, ss_q);

    for (int l = 0; l < L_; l++) {
        // qkv = rope( rms-scale(x) * Wqkv^T )
        LAUNCH_GEMM(128, 3, true, true, false, 16, 24, xb,
                    WqkvB + (size_t)l * 3 * D_ * D_, Wqkv + (size_t)l * 3 * D_ * D_,
                    qkv, nullptr, ss_q + (size_t)l * NT, nullptr, nullptr, (int)NT, 3 * D_, D_);
        k_attn_pair<<<dim3(8, B_ * H_), dim3(256), 0, stream>>>(qkv, ctxb);
        // x += ctx*Wout^T ; emit xb mirror + ss for FFN norm
        LAUNCH_GEMM(64, 1, false, false, true, 16, 16, ctxb,
                    WoutB + (size_t)l * D_ * D_, Wout + (size_t)l * D_ * D_,
                    xbuf, xbuf, nullptr, ss_f + (size_t)l * NT, xb, (int)NT, D_, D_);
        // h = relu( rms-scale(x)*W1^T )^2
        LAUNCH_GEMM(128, 2, true, true, false, 16, 32, xb,
                    W1B + (size_t)l * 4 * D_ * D_, W1 + (size_t)l * 4 * D_ * D_,
                    hb, nullptr, ss_f + (size_t)l * NT, nullptr, nullptr, (int)NT, 4 * D_, D_);
        // x += h*W2^T ; emit xb mirror + ss for next qkv norm (or lm_head)
        LAUNCH_GEMM(64, 1, false, false, true, 16, 16, hb,
                    W2B + (size_t)l * 4 * D_ * D_, W2 + (size_t)l * 4 * D_ * D_,
                    xbuf, xbuf, nullptr, ss_q + (size_t)(l + 1) * NT, xb, (int)NT, D_, 4 * D_);
    }
    // logits = rms-scale(x) * lmh^T
    LAUNCH_GEMM(256, 0, false, true, false, 16, 125, xb, lmhB, lmh, out, nullptr,
                ss_q + (size_t)L_ * NT, nullptr, nullptr, (int)NT, V_, D_);
#undef LAUNCH_GEMM
}